// Round 1
// baseline (351.145 us; speedup 1.0000x reference)
//
#include <hip/hip_runtime.h>

#define KH 18          // total harmonics
#define NPTS (128*128*128)
#define BB 4           // batch

__global__ __launch_bounds__(256) void dddm_kernel(
    const float* __restrict__ input_t,
    const float* __restrict__ poly,    // [N,4]
    const float* __restrict__ fa,      // [N,18]
    const float* __restrict__ fb,      // [N,18]
    const int*   __restrict__ stage_p,
    float* __restrict__ out)           // [2,B,N] concat: y_poly then y_fourier
{
    __shared__ float ct[BB][KH];
    __shared__ float st[BB][KH];
    __shared__ float tp[BB][4];

    const int tid = threadIdx.x;
    if (tid < BB * KH) {
        const int b = tid / KH, k = tid % KH;
        const float t = input_t[b];
        const float ph = 6.283185307179586f * (float)(k + 1) * t;
        float s, c;
        sincosf(ph, &s, &c);
        ct[b][k] = c;
        st[b][k] = s;
    } else if (tid < BB * KH + BB) {
        const int b = tid - BB * KH;
        const float t = input_t[b];
        tp[b][0] = 1.0f;
        tp[b][1] = t;
        tp[b][2] = t * t;
        tp[b][3] = t * t * t;
    }

    // stage gating (wave-uniform)
    const int ms = *stage_p;
    const int cs = (ms >= 0) ? (ms < 3 ? ms : 3) : 3;
    const int kmax = (cs >= 3) ? 18 : (cs == 2 ? 9 : (cs == 1 ? 3 : 0));

    __syncthreads();

    const int n = blockIdx.x * blockDim.x + threadIdx.x;
    if (n >= NPTS) return;

    // ---- polynomial part: row is 16B and 16B-aligned -> float4 ----
    const float4 c4 = reinterpret_cast<const float4*>(poly)[n];
    float yp[BB];
#pragma unroll
    for (int b = 0; b < BB; ++b)
        yp[b] = c4.x * tp[b][0] + c4.y * tp[b][1] + c4.z * tp[b][2] + c4.w * tp[b][3];

    // ---- fourier part ----
    float yf[BB] = {0.f, 0.f, 0.f, 0.f};
    if (kmax == KH) {
        // fast path: rows are 72B (8B-aligned) -> 9x float2 vector loads
        float2 a2[9], b2[9];
        const float2* ar = reinterpret_cast<const float2*>(fa + (size_t)n * KH);
        const float2* br = reinterpret_cast<const float2*>(fb + (size_t)n * KH);
#pragma unroll
        for (int j = 0; j < 9; ++j) { a2[j] = ar[j]; b2[j] = br[j]; }
        const float* av = reinterpret_cast<const float*>(a2);
        const float* bv = reinterpret_cast<const float*>(b2);
#pragma unroll
        for (int k = 0; k < KH; ++k) {
            const float ak = av[k], bk = bv[k];
#pragma unroll
            for (int b = 0; b < BB; ++b)
                yf[b] += ak * ct[b][k] + bk * st[b][k];
        }
    } else if (kmax > 0) {
        for (int k = 0; k < kmax; ++k) {
            const float ak = fa[(size_t)n * KH + k];
            const float bk = fb[(size_t)n * KH + k];
#pragma unroll
            for (int b = 0; b < BB; ++b)
                yf[b] += ak * ct[b][k] + bk * st[b][k];
        }
    }

    // ---- store: coalesced per (output, b) plane ----
#pragma unroll
    for (int b = 0; b < BB; ++b) {
        out[(size_t)b * NPTS + n]            = yp[b];
        out[(size_t)(BB + b) * NPTS + n]     = yf[b];
    }
}

extern "C" void kernel_launch(void* const* d_in, const int* in_sizes, int n_in,
                              void* d_out, int out_size, void* d_ws, size_t ws_size,
                              hipStream_t stream) {
    const float* input_t = (const float*)d_in[0];
    const float* poly    = (const float*)d_in[1];
    const float* fa      = (const float*)d_in[2];
    const float* fb      = (const float*)d_in[3];
    const int*   stage   = (const int*)d_in[4];
    float* out = (float*)d_out;

    dddm_kernel<<<NPTS / 256, 256, 0, stream>>>(input_t, poly, fa, fb, stage, out);
}

// Round 2
// 349.288 us; speedup vs baseline: 1.0053x; 1.0053x over previous
//
#include <hip/hip_runtime.h>

#define KH 18          // total harmonics
#define NPTS (128*128*128)
#define BB 4           // batch
#define BLK 256
#define ROW_FLOATS (BLK * KH)          // 4608 floats per array per block

__global__ __launch_bounds__(256, 4) void dddm_kernel(
    const float* __restrict__ input_t,
    const float* __restrict__ poly,    // [N,4]
    const float* __restrict__ fa,      // [N,18]
    const float* __restrict__ fb,      // [N,18]
    const int*   __restrict__ stage_p,
    float* __restrict__ out)           // [2,B,N] concat: y_poly then y_fourier
{
    __shared__ float s[2 * ROW_FLOATS];     // [0,4608): fa tile, [4608,9216): fb tile
    __shared__ float ct[BB][KH];
    __shared__ float st[BB][KH];
    __shared__ float tp[BB][4];

    const int tid = threadIdx.x;
    const int n0  = blockIdx.x * BLK;

    // ---- tiny trig / power tables (computed once per block) ----
    if (tid < BB * KH) {
        const int b = tid / KH, k = tid % KH;
        const float t = input_t[b];
        const float ph = 6.283185307179586f * (float)(k + 1) * t;
        float sn, cs;
        sincosf(ph, &sn, &cs);
        ct[b][k] = cs;
        st[b][k] = sn;
    } else if (tid < BB * KH + BB) {
        const int b = tid - BB * KH;
        const float t = input_t[b];
        tp[b][0] = 1.0f;
        tp[b][1] = t;
        tp[b][2] = t * t;
        tp[b][3] = t * t * t;
    }

    // ---- coalesced staging: both fourier tiles, float4, 9 per thread ----
    // fa tile starts at byte n0*72 (n0 % 256 == 0 -> 16B aligned)
    const float4* fa4 = reinterpret_cast<const float4*>(fa + (size_t)n0 * KH);
    const float4* fb4 = reinterpret_cast<const float4*>(fb + (size_t)n0 * KH);
    float4* s4 = reinterpret_cast<float4*>(s);

    float4 v[9];
#pragma unroll
    for (int j = 0; j < 9; ++j) {
        const int idx = j * BLK + tid;              // 0..2303
        v[j] = (idx < ROW_FLOATS / 4) ? fa4[idx] : fb4[idx - ROW_FLOATS / 4];
    }
#pragma unroll
    for (int j = 0; j < 9; ++j) {
        const int idx = j * BLK + tid;
        s4[idx] = v[j];                             // linear: same index -> contiguous
    }

    // stage gating (wave-uniform scalar)
    const int ms = *stage_p;
    const int cs = (ms >= 0) ? (ms < 3 ? ms : 3) : 3;
    const int kmax = (cs >= 3) ? 18 : (cs == 2 ? 9 : (cs == 1 ? 3 : 0));

    __syncthreads();

    const int n = n0 + tid;

    // ---- polynomial part: row is 16B and 16B-aligned -> float4 ----
    const float4 c4 = reinterpret_cast<const float4*>(poly)[n];
    float yp[BB];
#pragma unroll
    for (int b = 0; b < BB; ++b)
        yp[b] = c4.x * tp[b][0] + c4.y * tp[b][1] + c4.z * tp[b][2] + c4.w * tp[b][3];

    // ---- fourier part: read own row from LDS (float2 -> ds_read_b64) ----
    float av[KH], bv[KH];
    {
        const float2* ar = reinterpret_cast<const float2*>(s + tid * KH);
        const float2* br = reinterpret_cast<const float2*>(s + ROW_FLOATS + tid * KH);
#pragma unroll
        for (int j = 0; j < 9; ++j) {
            const float2 a2 = ar[j];
            const float2 b2 = br[j];
            av[2 * j] = a2.x; av[2 * j + 1] = a2.y;
            bv[2 * j] = b2.x; bv[2 * j + 1] = b2.y;
        }
    }

    float yf[BB] = {0.f, 0.f, 0.f, 0.f};
    if (kmax == KH) {
#pragma unroll
        for (int k = 0; k < KH; ++k) {
            const float ak = av[k], bk = bv[k];
#pragma unroll
            for (int b = 0; b < BB; ++b)
                yf[b] += ak * ct[b][k] + bk * st[b][k];
        }
    } else if (kmax > 0) {
        for (int k = 0; k < kmax; ++k) {
            const float ak = av[k], bk = bv[k];
#pragma unroll
            for (int b = 0; b < BB; ++b)
                yf[b] += ak * ct[b][k] + bk * st[b][k];
        }
    }

    // ---- store: coalesced dword per (output, b) plane ----
#pragma unroll
    for (int b = 0; b < BB; ++b) {
        out[(size_t)b * NPTS + n]        = yp[b];
        out[(size_t)(BB + b) * NPTS + n] = yf[b];
    }
}

extern "C" void kernel_launch(void* const* d_in, const int* in_sizes, int n_in,
                              void* d_out, int out_size, void* d_ws, size_t ws_size,
                              hipStream_t stream) {
    const float* input_t = (const float*)d_in[0];
    const float* poly    = (const float*)d_in[1];
    const float* fa      = (const float*)d_in[2];
    const float* fb      = (const float*)d_in[3];
    const int*   stage   = (const int*)d_in[4];
    float* out = (float*)d_out;

    dddm_kernel<<<NPTS / BLK, BLK, 0, stream>>>(input_t, poly, fa, fb, stage, out);
}